// Round 4
// baseline (1059.281 us; speedup 1.0000x reference)
//
#include <hip/hip_runtime.h>

// Problem constants
constexpr int B  = 4;
constexpr int C  = 256;
constexpr int HH = 48;
constexpr int WW = 48;
constexpr int N  = HH * WW;   // 2304
constexpr int NH = 8;
constexpr int DK = 32;        // C / NH

// ---------------------------------------------------------------------------
// Projection GEMM: q/k/v[b][n][o] = sum_c x[b][c][n] * w[o][c]
// ws layout: mat-major, per-mat stride matStride elems; batch offset
// b*batchStride (batchStride = N*C for full-batch layout, 0 for per-batch).
// Tile: 64 n x 64 o, KT=16. 256 threads, each computes 4x4 outputs.
// ---------------------------------------------------------------------------
__global__ __launch_bounds__(256) void proj_kernel(
    const float* __restrict__ x,
    const float* __restrict__ wq,
    const float* __restrict__ wk,
    const float* __restrict__ wv,
    float* __restrict__ ws,
    int bfix, size_t matStride, size_t batchStride)
{
    const int tile = blockIdx.x;          // 0..143
    const int mat  = blockIdx.y;          // 0..2
    const int b    = (bfix >= 0) ? bfix : (int)blockIdx.z;
    const int nt = tile % (N / 64);       // 0..35
    const int ot = tile / (N / 64);       // 0..3
    const int n0 = nt * 64;
    const int o0 = ot * 64;

    const float* w = (mat == 0) ? wq : (mat == 1) ? wk : wv;
    float* out = ws + (size_t)mat * matStride + (size_t)b * batchStride;
    const float* xb = x + (size_t)b * C * N;

    __shared__ float xs[16][64];      // [kk][nn]
    __shared__ float wt[64][17];      // [oo][kk], padded

    const int tid = threadIdx.x;
    const int tx = tid & 15;          // n quadrant
    const int ty = tid >> 4;          // o quadrant

    float acc[4][4] = {};             // acc[jo][jn]

    for (int k0 = 0; k0 < C; k0 += 16) {
        {   // stage X tile: 16x64 floats = 256 float4, one per thread
            const int kk  = tid >> 4;   // 0..15
            const int nn4 = tid & 15;   // 0..15
            float4 v = *reinterpret_cast<const float4*>(xb + (size_t)(k0 + kk) * N + n0 + nn4 * 4);
            *reinterpret_cast<float4*>(&xs[kk][nn4 * 4]) = v;
        }
        {   // stage W tile: 64x16 floats = 256 float4, one per thread
            const int oo = tid >> 2;    // 0..63
            const int k4 = tid & 3;     // 0..3
            float4 v = *reinterpret_cast<const float4*>(w + (size_t)(o0 + oo) * C + k0 + k4 * 4);
            wt[oo][k4 * 4 + 0] = v.x;
            wt[oo][k4 * 4 + 1] = v.y;
            wt[oo][k4 * 4 + 2] = v.z;
            wt[oo][k4 * 4 + 3] = v.w;
        }
        __syncthreads();

        #pragma unroll
        for (int kk = 0; kk < 16; ++kk) {
            float4 a = *reinterpret_cast<const float4*>(&xs[kk][tx * 4]);
            float av[4] = {a.x, a.y, a.z, a.w};
            float bv[4];
            #pragma unroll
            for (int jo = 0; jo < 4; ++jo) bv[jo] = wt[ty * 4 + jo][kk];
            #pragma unroll
            for (int jo = 0; jo < 4; ++jo)
                #pragma unroll
                for (int jn = 0; jn < 4; ++jn)
                    acc[jo][jn] = fmaf(bv[jo], av[jn], acc[jo][jn]);
        }
        __syncthreads();
    }

    // write out[n][o], o contiguous -> float4 per jn
    #pragma unroll
    for (int jn = 0; jn < 4; ++jn) {
        float4 v = make_float4(acc[0][jn], acc[1][jn], acc[2][jn], acc[3][jn]);
        *reinterpret_cast<float4*>(out + (size_t)(n0 + tx * 4 + jn) * C + o0 + ty * 4) = v;
    }
}

// ---------------------------------------------------------------------------
// Flash attention, f32. One thread = one query row; block = 64 threads = 64
// rows of one (b,h). K/V staged in LDS 64 keys at a time. Online softmax with
// rarely-taken rescale branch. Residual add fused into the epilogue.
// ---------------------------------------------------------------------------
__global__ __launch_bounds__(64) void attn_kernel(
    const float* __restrict__ ws,
    const float* __restrict__ x,
    float* __restrict__ out,
    int bfix, size_t matStride, size_t batchStride)
{
    const int b = (bfix >= 0) ? bfix : (int)blockIdx.z;
    const int h = blockIdx.y;
    const int t = threadIdx.x;                 // 0..63
    const int n = blockIdx.x * 64 + t;         // query row

    const float* qbuf = ws + (size_t)b * batchStride;
    const float* kbuf = ws + matStride + (size_t)b * batchStride;
    const float* vbuf = ws + 2 * matStride + (size_t)b * batchStride;

    __shared__ float ks[64][32];
    __shared__ float vs[64][32];

    float qr[32];
    float acc[32] = {};

    {
        const float* qp = qbuf + (size_t)n * C + h * DK;
        const float rs = 0.17677669529663687f;   // 1/sqrt(32)
        #pragma unroll
        for (int j = 0; j < 8; ++j) {
            float4 v = *reinterpret_cast<const float4*>(qp + j * 4);
            qr[j * 4 + 0] = v.x * rs;
            qr[j * 4 + 1] = v.y * rs;
            qr[j * 4 + 2] = v.z * rs;
            qr[j * 4 + 3] = v.w * rs;
        }
    }

    float mrun = -1e30f;
    float lrun = 0.0f;

    for (int m0 = 0; m0 < N; m0 += 64) {
        // stage K,V tile: 64 rows x 32 floats each = 512 float4 per matrix
        const float* kp = kbuf + (size_t)m0 * C + h * DK;
        const float* vp = vbuf + (size_t)m0 * C + h * DK;
        #pragma unroll
        for (int i = 0; i < 8; ++i) {
            const int f  = t + 64 * i;     // 0..511
            const int mm = f >> 3;
            const int d4 = f & 7;
            *reinterpret_cast<float4*>(&ks[mm][d4 * 4]) =
                *reinterpret_cast<const float4*>(kp + (size_t)mm * C + d4 * 4);
            *reinterpret_cast<float4*>(&vs[mm][d4 * 4]) =
                *reinterpret_cast<const float4*>(vp + (size_t)mm * C + d4 * 4);
        }
        __syncthreads();

        #pragma unroll 2
        for (int mm = 0; mm < 64; ++mm) {
            // score = dot(q_row, k_row): 8 float4 broadcast reads, 4 chains
            float s0 = 0.f, s1 = 0.f, s2 = 0.f, s3 = 0.f;
            #pragma unroll
            for (int j = 0; j < 8; ++j) {
                float4 kv = *reinterpret_cast<const float4*>(&ks[mm][j * 4]);
                s0 = fmaf(qr[j * 4 + 0], kv.x, s0);
                s1 = fmaf(qr[j * 4 + 1], kv.y, s1);
                s2 = fmaf(qr[j * 4 + 2], kv.z, s2);
                s3 = fmaf(qr[j * 4 + 3], kv.w, s3);
            }
            float s = (s0 + s1) + (s2 + s3);

            float p;
            if (s <= mrun) {
                p = __expf(s - mrun);
            } else {
                // new running max: rescale state (rare -> divergence acceptable)
                float corr = __expf(mrun - s);
                #pragma unroll
                for (int d = 0; d < 32; ++d) acc[d] *= corr;
                lrun *= corr;
                mrun = s;
                p = 1.0f;
            }
            lrun += p;

            #pragma unroll
            for (int j = 0; j < 8; ++j) {
                float4 vv = *reinterpret_cast<const float4*>(&vs[mm][j * 4]);
                acc[j * 4 + 0] = fmaf(p, vv.x, acc[j * 4 + 0]);
                acc[j * 4 + 1] = fmaf(p, vv.y, acc[j * 4 + 1]);
                acc[j * 4 + 2] = fmaf(p, vv.z, acc[j * 4 + 2]);
                acc[j * 4 + 3] = fmaf(p, vv.w, acc[j * 4 + 3]);
            }
        }
        __syncthreads();
    }

    // epilogue: out[b][h*32+d][n] = x[b][h*32+d][n] + acc[d]/lrun
    const float inv = 1.0f / lrun;
    const size_t base = ((size_t)b * C + h * DK) * (size_t)N + n;
    #pragma unroll
    for (int d = 0; d < 32; ++d) {
        out[base + (size_t)d * N] = x[base + (size_t)d * N] + acc[d] * inv;
    }
}

extern "C" void kernel_launch(void* const* d_in, const int* in_sizes, int n_in,
                              void* d_out, int out_size, void* d_ws, size_t ws_size,
                              hipStream_t stream) {
    const float* x  = (const float*)d_in[0];
    const float* wq = (const float*)d_in[1];
    const float* wk = (const float*)d_in[2];
    const float* wv = (const float*)d_in[3];
    float* out = (float*)d_out;
    float* ws  = (float*)d_ws;

    const size_t NC  = (size_t)N * C;                 // per-batch per-mat elems
    const size_t needFull  = 3 * (size_t)B * NC * sizeof(float);  // 28.3 MB
    const size_t needBatch = 3 * NC * sizeof(float);              // 7.08 MB

    if (ws_size >= needFull) {
        // Full-batch layout: ws = [q|k|v], each [B][N][C]
        proj_kernel<<<dim3((N / 64) * (C / 64), 3, B), 256, 0, stream>>>(
            x, wq, wk, wv, ws, -1, (size_t)B * NC, NC);
        attn_kernel<<<dim3(N / 64, NH, B), 64, 0, stream>>>(
            ws, x, out, -1, (size_t)B * NC, NC);
    } else {
        // Per-batch layout: ws = [q|k|v], each [N][C]; batches serialized on
        // the stream (proj_b -> attn_b -> proj_{b+1} -> ...). Needs 7.08 MB.
        for (int b = 0; b < B; ++b) {
            proj_kernel<<<dim3((N / 64) * (C / 64), 3, 1), 256, 0, stream>>>(
                x, wq, wk, wv, ws, b, NC, 0);
            attn_kernel<<<dim3(N / 64, NH, 1), 64, 0, stream>>>(
                ws, x, out, b, NC, 0);
        }
    }
}

// Round 5
// 232.064 us; speedup vs baseline: 4.5646x; 4.5646x over previous
//
#include <hip/hip_runtime.h>

constexpr int B  = 4;
constexpr int C  = 256;
constexpr int N  = 2304;   // 48*48
constexpr int NH = 8;
constexpr int DK = 32;     // C / NH

typedef short short8 __attribute__((ext_vector_type(8)));   // 8 bf16 (raw bits)
typedef float f32x4  __attribute__((ext_vector_type(4)));

// f32 -> bf16 bits, round-to-nearest-even
static __device__ __forceinline__ ushort f2bf(float f) {
    union { float f; unsigned u; } v; v.f = f;
    unsigned r = (v.u + 0x7FFFu + ((v.u >> 16) & 1u)) >> 16;
    return (ushort)r;
}

// ---------------------------------------------------------------------------
// Projection GEMM: q/k/v[b][n][o] = sum_c x[b][c][n] * w[o][c], emitted bf16.
// rs = 1/sqrt(d_k) folded into q. Tile 64n x 64o, KT=16, 256 thr, 4x4/thread.
// ---------------------------------------------------------------------------
__global__ __launch_bounds__(256) void proj_kernel(
    const float* __restrict__ x,
    const float* __restrict__ wq,
    const float* __restrict__ wk,
    const float* __restrict__ wv,
    ushort* __restrict__ ws,
    int bfix, size_t matStride, size_t batchStride)
{
    const int tile = blockIdx.x;          // 0..143
    const int mat  = blockIdx.y;          // 0..2
    const int b    = (bfix >= 0) ? bfix : (int)blockIdx.z;
    const int nt = tile % (N / 64);
    const int ot = tile / (N / 64);
    const int n0 = nt * 64;
    const int o0 = ot * 64;

    const float* w = (mat == 0) ? wq : (mat == 1) ? wk : wv;
    ushort* out = ws + (size_t)mat * matStride + (size_t)b * batchStride;
    const float* xb = x + (size_t)b * C * N;

    __shared__ float xs[16][64];
    __shared__ float wt[64][17];

    const int tid = threadIdx.x;
    const int tx = tid & 15;
    const int ty = tid >> 4;

    float acc[4][4] = {};

    for (int k0 = 0; k0 < C; k0 += 16) {
        {
            const int kk  = tid >> 4;
            const int nn4 = tid & 15;
            float4 v = *reinterpret_cast<const float4*>(xb + (size_t)(k0 + kk) * N + n0 + nn4 * 4);
            *reinterpret_cast<float4*>(&xs[kk][nn4 * 4]) = v;
        }
        {
            const int oo = tid >> 2;
            const int k4 = tid & 3;
            float4 v = *reinterpret_cast<const float4*>(w + (size_t)(o0 + oo) * C + k0 + k4 * 4);
            wt[oo][k4 * 4 + 0] = v.x;
            wt[oo][k4 * 4 + 1] = v.y;
            wt[oo][k4 * 4 + 2] = v.z;
            wt[oo][k4 * 4 + 3] = v.w;
        }
        __syncthreads();

        #pragma unroll
        for (int kk = 0; kk < 16; ++kk) {
            float4 a = *reinterpret_cast<const float4*>(&xs[kk][tx * 4]);
            float av[4] = {a.x, a.y, a.z, a.w};
            float bv[4];
            #pragma unroll
            for (int jo = 0; jo < 4; ++jo) bv[jo] = wt[ty * 4 + jo][kk];
            #pragma unroll
            for (int jo = 0; jo < 4; ++jo)
                #pragma unroll
                for (int jn = 0; jn < 4; ++jn)
                    acc[jo][jn] = fmaf(bv[jo], av[jn], acc[jo][jn]);
        }
        __syncthreads();
    }

    const float sc = (mat == 0) ? 0.17677669529663687f : 1.0f;  // 1/sqrt(32) into q
    #pragma unroll
    for (int jn = 0; jn < 4; ++jn) {
        ushort4 wv4 = make_ushort4(f2bf(acc[0][jn] * sc), f2bf(acc[1][jn] * sc),
                                   f2bf(acc[2][jn] * sc), f2bf(acc[3][jn] * sc));
        *reinterpret_cast<ushort4*>(out + (size_t)(n0 + tx * 4 + jn) * C + o0 + ty * 4) = wv4;
    }
}

// ---------------------------------------------------------------------------
// MFMA flash attention. Block = 256 thr = 4 waves; wave owns 16 q-rows.
// Swapped QK^T (A=K,B=Q -> S^T): per-lane scalar softmax state (q = lane&15),
// P lands 4-consecutive-keys/lane -> b64 writes to P_lds, b128 A-frag reads.
// K: LDS [64][40] bf16 (pad). V: transposed [32][72]. Epilogue via LDS for
// coalesced float4 out + residual. 1-D grid with XCD-affine (b,h) mapping.
// ---------------------------------------------------------------------------
__global__ __launch_bounds__(256) void attn_kernel(
    const ushort* __restrict__ ws,
    const float* __restrict__ x,
    float* __restrict__ out,
    int bfix, size_t matStride, size_t batchStride, int ppx)
{
    __shared__ __align__(16) char smem[18944];
    ushort* Ks  = (ushort*)smem;             // [64][40]
    ushort* Vt  = (ushort*)(smem + 5120);    // [32][72]
    float*  Ost = (float*) smem;             // [32][68]  (reuses Ks+Vt region)

    const int tid = threadIdx.x;
    const int wq = tid >> 6;         // wave 0..3
    const int l  = tid & 63;
    const int lq = l & 15;
    const int g  = l >> 4;

    ushort* Pl = (ushort*)(smem + 9728) + wq * 1152;   // wave's [16][72]

    // XCD-affine decode: consecutive blockIdx round-robin XCDs (gid&7 = XCD);
    // give each XCD whole (b,h) pairs so its K/V set (~1.2MB) is L2-resident.
    const int gid  = blockIdx.x;
    const int xcd  = gid & 7;
    const int loc  = gid >> 3;
    const int pair = xcd * ppx + loc / 36;
    const int qt   = loc % 36;
    const int h    = pair & 7;
    const int b    = (bfix >= 0) ? bfix : (pair >> 3);
    const int n0   = qt * 64;

    const ushort* qb = ws + (size_t)b * batchStride;
    const ushort* kb = qb + matStride;
    const ushort* vb = qb + 2 * matStride;

    // Q fragment: lane supplies Q[q=lq][k = 8g..8g+7]  (A/B frag gather)
    short8 qf = *reinterpret_cast<const short8*>(
        qb + (size_t)(n0 + wq * 16 + lq) * C + h * DK + 8 * g);

    f32x4 acc0 = {0.f, 0.f, 0.f, 0.f};
    f32x4 acc1 = {0.f, 0.f, 0.f, 0.f};
    float m = -1e30f, lsum = 0.f;

    const int srow = tid >> 2, sch = tid & 3;   // K staging: 16B per thread
    const int kp = tid & 31, dg = tid >> 5;     // V staging: 2 keys x 4 d's

    for (int m0 = 0; m0 < N; m0 += 64) {
        // ---- stage K tile [64 keys][32 d] -> Ks[64][40]
        *reinterpret_cast<short8*>(Ks + srow * 40 + sch * 8) =
            *reinterpret_cast<const short8*>(kb + (size_t)(m0 + srow) * C + h * DK + sch * 8);
        // ---- stage V tile transposed -> Vt[d][key], keys packed in pairs
        {
            const ushort* v0 = vb + (size_t)(m0 + 2 * kp) * C + h * DK + dg * 4;
            ushort4 a  = *reinterpret_cast<const ushort4*>(v0);
            ushort4 c4 = *reinterpret_cast<const ushort4*>(v0 + C);
            *reinterpret_cast<unsigned*>(Vt + (dg * 4 + 0) * 72 + 2 * kp) = (unsigned)a.x | ((unsigned)c4.x << 16);
            *reinterpret_cast<unsigned*>(Vt + (dg * 4 + 1) * 72 + 2 * kp) = (unsigned)a.y | ((unsigned)c4.y << 16);
            *reinterpret_cast<unsigned*>(Vt + (dg * 4 + 2) * 72 + 2 * kp) = (unsigned)a.z | ((unsigned)c4.z << 16);
            *reinterpret_cast<unsigned*>(Vt + (dg * 4 + 3) * 72 + 2 * kp) = (unsigned)a.w | ((unsigned)c4.w << 16);
        }
        __syncthreads();

        // ---- QK^T swapped: S^T[key][q]; lane holds keys 4g+r (+16t), q=lq
        f32x4 st[4];
        #pragma unroll
        for (int t = 0; t < 4; ++t) {
            short8 kf = *reinterpret_cast<const short8*>(Ks + (lq + 16 * t) * 40 + 8 * g);
            f32x4 z = {0.f, 0.f, 0.f, 0.f};
            st[t] = __builtin_amdgcn_mfma_f32_16x16x32_bf16(kf, qf, z, 0, 0, 0);
        }

        // ---- online softmax (scalar state per lane)
        float mx = st[0][0];
        #pragma unroll
        for (int t = 0; t < 4; ++t)
            #pragma unroll
            for (int r = 0; r < 4; ++r) mx = fmaxf(mx, st[t][r]);
        mx = fmaxf(mx, __shfl_xor(mx, 16));
        mx = fmaxf(mx, __shfl_xor(mx, 32));
        const float newm = fmaxf(m, mx);
        const float corr = __expf(m - newm);
        m = newm;

        float ps = 0.f;
        ushort pb[16];
        #pragma unroll
        for (int t = 0; t < 4; ++t)
            #pragma unroll
            for (int r = 0; r < 4; ++r) {
                float p = __expf(st[t][r] - m);
                ps += p;
                pb[t * 4 + r] = f2bf(p);
            }
        ps += __shfl_xor(ps, 16);
        ps += __shfl_xor(ps, 32);
        lsum = lsum * corr + ps;

        // O-rescale: O rows are q = 4g+reg -> fetch corr from lane (4g+reg)
        float cw[4];
        #pragma unroll
        for (int r = 0; r < 4; ++r) cw[r] = __shfl(corr, 4 * g + r);
        #pragma unroll
        for (int r = 0; r < 4; ++r) { acc0[r] *= cw[r]; acc1[r] *= cw[r]; }

        // ---- P -> LDS (P[q][key]; lane's 4 consecutive keys -> one b64)
        #pragma unroll
        for (int t = 0; t < 4; ++t) {
            ushort4 w4 = make_ushort4(pb[4 * t], pb[4 * t + 1], pb[4 * t + 2], pb[4 * t + 3]);
            *reinterpret_cast<ushort4*>(Pl + lq * 72 + 4 * g + 16 * t) = w4;
        }

        // ---- PV: A = P[16q x 32k], B = V[32k x 16d] (from Vt rows)
        short8 pf0 = *reinterpret_cast<const short8*>(Pl + lq * 72 + 8 * g);
        short8 pf1 = *reinterpret_cast<const short8*>(Pl + lq * 72 + 32 + 8 * g);
        #pragma unroll
        for (int kc = 0; kc < 2; ++kc) {
            short8 pf = kc ? pf1 : pf0;
            short8 vf0 = *reinterpret_cast<const short8*>(Vt + lq * 72 + 32 * kc + 8 * g);
            short8 vf1 = *reinterpret_cast<const short8*>(Vt + (lq + 16) * 72 + 32 * kc + 8 * g);
            acc0 = __builtin_amdgcn_mfma_f32_16x16x32_bf16(pf, vf0, acc0, 0, 0, 0);
            acc1 = __builtin_amdgcn_mfma_f32_16x16x32_bf16(pf, vf1, acc1, 0, 0, 0);
        }
        __syncthreads();
    }

    // ---- epilogue: normalize, stage O^T[d][n] in LDS, coalesced out + residual
    const float iv = 1.0f / lsum;
    float iw[4];
    #pragma unroll
    for (int r = 0; r < 4; ++r) iw[r] = __shfl(iv, 4 * g + r);
    #pragma unroll
    for (int r = 0; r < 4; ++r) {
        Ost[(lq +  0) * 68 + wq * 16 + 4 * g + r] = acc0[r] * iw[r];
        Ost[(lq + 16) * 68 + wq * 16 + 4 * g + r] = acc1[r] * iw[r];
    }
    __syncthreads();

    {
        const int d  = tid >> 3;
        const int nn = (tid & 7) * 8;
        const size_t go = ((size_t)b * C + h * DK + d) * (size_t)N + n0 + nn;
        float4 o1 = *reinterpret_cast<float4*>(Ost + d * 68 + nn);
        float4 o2 = *reinterpret_cast<float4*>(Ost + d * 68 + nn + 4);
        float4 x1 = *reinterpret_cast<const float4*>(x + go);
        float4 x2 = *reinterpret_cast<const float4*>(x + go + 4);
        *reinterpret_cast<float4*>(out + go)     = make_float4(o1.x + x1.x, o1.y + x1.y, o1.z + x1.z, o1.w + x1.w);
        *reinterpret_cast<float4*>(out + go + 4) = make_float4(o2.x + x2.x, o2.y + x2.y, o2.z + x2.z, o2.w + x2.w);
    }
}

extern "C" void kernel_launch(void* const* d_in, const int* in_sizes, int n_in,
                              void* d_out, int out_size, void* d_ws, size_t ws_size,
                              hipStream_t stream) {
    const float* x  = (const float*)d_in[0];
    const float* wq = (const float*)d_in[1];
    const float* wk = (const float*)d_in[2];
    const float* wv = (const float*)d_in[3];
    float* out = (float*)d_out;
    ushort* ws = (ushort*)d_ws;

    const size_t NC = (size_t)N * C;
    const size_t needFull = 3 * (size_t)B * NC * sizeof(ushort);   // 14.2 MB

    if (ws_size >= needFull) {
        proj_kernel<<<dim3((N / 64) * (C / 64), 3, B), 256, 0, stream>>>(
            x, wq, wk, wv, ws, -1, (size_t)B * NC, NC);
        attn_kernel<<<dim3(36 * NH * B), 256, 0, stream>>>(
            ws, x, out, -1, (size_t)B * NC, NC, 4);
    } else {
        // per-batch fallback (3.5 MB): proj_b -> attn_b serialized on stream
        for (int b = 0; b < B; ++b) {
            proj_kernel<<<dim3((N / 64) * (C / 64), 3, 1), 256, 0, stream>>>(
                x, wq, wk, wv, ws, b, NC, 0);
            attn_kernel<<<dim3(36 * NH), 256, 0, stream>>>(
                ws, x, out, b, NC, 0, 1);
        }
    }
}

// Round 6
// 229.632 us; speedup vs baseline: 4.6130x; 1.0106x over previous
//
#include <hip/hip_runtime.h>

constexpr int B  = 4;
constexpr int C  = 256;
constexpr int N  = 2304;   // 48*48
constexpr int NH = 8;
constexpr int DK = 32;     // C / NH

typedef short short8 __attribute__((ext_vector_type(8)));   // 8 bf16 (raw bits)
typedef float f32x4  __attribute__((ext_vector_type(4)));

// f32 -> bf16 bits, round-to-nearest-even (proj epilogue)
static __device__ __forceinline__ ushort f2bf(float f) {
    union { float f; unsigned u; } v; v.f = f;
    return (ushort)((v.u + 0x7FFFu + ((v.u >> 16) & 1u)) >> 16);
}
// packed f32x2 -> bf16x2 (hardware RTNE)
static __device__ __forceinline__ unsigned cvtpk(float lo, float hi) {
    unsigned r;
    asm("v_cvt_pk_bf16_f32 %0, %1, %2" : "=v"(r) : "v"(lo), "v"(hi));
    return r;
}

// ---------------------------------------------------------------------------
// Projection GEMM: q/k/v[b][n][o] = sum_c x[b][c][n] * w[o][c], emitted bf16.
// q scaled by log2(e)/sqrt(d_k) so attention works in exp2 domain.
// ---------------------------------------------------------------------------
__global__ __launch_bounds__(256) void proj_kernel(
    const float* __restrict__ x,
    const float* __restrict__ wq,
    const float* __restrict__ wk,
    const float* __restrict__ wv,
    ushort* __restrict__ ws,
    int bfix, size_t matStride, size_t batchStride)
{
    const int tile = blockIdx.x;
    const int mat  = blockIdx.y;
    const int b    = (bfix >= 0) ? bfix : (int)blockIdx.z;
    const int n0 = (tile % (N / 64)) * 64;
    const int o0 = (tile / (N / 64)) * 64;

    const float* w = (mat == 0) ? wq : (mat == 1) ? wk : wv;
    ushort* out = ws + (size_t)mat * matStride + (size_t)b * batchStride;
    const float* xb = x + (size_t)b * C * N;

    __shared__ float xs[16][64];
    __shared__ float wt[64][17];

    const int tid = threadIdx.x;
    const int tx = tid & 15;
    const int ty = tid >> 4;

    float acc[4][4] = {};

    for (int k0 = 0; k0 < C; k0 += 16) {
        {
            const int kk  = tid >> 4;
            const int nn4 = tid & 15;
            float4 v = *reinterpret_cast<const float4*>(xb + (size_t)(k0 + kk) * N + n0 + nn4 * 4);
            *reinterpret_cast<float4*>(&xs[kk][nn4 * 4]) = v;
        }
        {
            const int oo = tid >> 2;
            const int k4 = tid & 3;
            float4 v = *reinterpret_cast<const float4*>(w + (size_t)(o0 + oo) * C + k0 + k4 * 4);
            wt[oo][k4 * 4 + 0] = v.x;
            wt[oo][k4 * 4 + 1] = v.y;
            wt[oo][k4 * 4 + 2] = v.z;
            wt[oo][k4 * 4 + 3] = v.w;
        }
        __syncthreads();

        #pragma unroll
        for (int kk = 0; kk < 16; ++kk) {
            float4 a = *reinterpret_cast<const float4*>(&xs[kk][tx * 4]);
            float av[4] = {a.x, a.y, a.z, a.w};
            float bv[4];
            #pragma unroll
            for (int jo = 0; jo < 4; ++jo) bv[jo] = wt[ty * 4 + jo][kk];
            #pragma unroll
            for (int jo = 0; jo < 4; ++jo)
                #pragma unroll
                for (int jn = 0; jn < 4; ++jn)
                    acc[jo][jn] = fmaf(bv[jo], av[jn], acc[jo][jn]);
        }
        __syncthreads();
    }

    // q: 1/sqrt(32) * log2(e)  (exp2-domain flash attention)
    const float sc = (mat == 0) ? 0.25503450535f : 1.0f;
    #pragma unroll
    for (int jn = 0; jn < 4; ++jn) {
        ushort4 wv4 = make_ushort4(f2bf(acc[0][jn] * sc), f2bf(acc[1][jn] * sc),
                                   f2bf(acc[2][jn] * sc), f2bf(acc[3][jn] * sc));
        *reinterpret_cast<ushort4*>(out + (size_t)(n0 + tx * 4 + jn) * C + o0 + ty * 4) = wv4;
    }
}

// ---------------------------------------------------------------------------
// MFMA flash attention, exp2 domain. Block = 128 thr = 2 waves; wave owns 16
// q-rows (QT=32/block -> 2304 blocks). Swapped QK^T -> per-lane scalar softmax
// state. Defer-max (THR=8): common path has no shuffles/rescale. K/V tile
// loads register-staged one tile ahead (async-split); ds_write after barrier.
// ---------------------------------------------------------------------------
__global__ __launch_bounds__(128) void attn_kernel(
    const ushort* __restrict__ ws,
    const float* __restrict__ x,
    float* __restrict__ out,
    int bfix, size_t matStride, size_t batchStride, int ppx)
{
    __shared__ __align__(16) char smem[14336];
    ushort* Ks  = (ushort*)smem;             // [64][40] bf16
    ushort* Vt  = (ushort*)(smem + 5120);    // [32][72] bf16 (V transposed)
    float*  Ost = (float*) smem;             // [32][36] f32 (epilogue reuse)

    const int tid = threadIdx.x;
    const int wq  = tid >> 6;        // wave 0..1
    const int l   = tid & 63;
    const int lq  = l & 15;
    const int g   = l >> 4;

    ushort* Pl = (ushort*)(smem + 9728) + wq * 1152;   // wave's P [16][72]

    // XCD-affine: gid&7 = XCD; each XCD owns whole (b,h) pairs.
    const int gid  = blockIdx.x;
    const int xcd  = gid & 7;
    const int loc  = gid >> 3;
    const int pair = xcd * ppx + loc / 72;
    const int qt   = loc % 72;
    const int h    = pair & 7;
    const int b    = (bfix >= 0) ? bfix : (pair >> 3);
    const int n0   = qt * 32;

    const ushort* qb = ws + (size_t)b * batchStride;
    const ushort* kb = qb + matStride;
    const ushort* vb = qb + 2 * matStride;

    // Q fragment: lane supplies Q[q=lq][d = 8g..8g+7]
    short8 qf = *reinterpret_cast<const short8*>(
        qb + (size_t)(n0 + wq * 16 + lq) * C + h * DK + 8 * g);

    f32x4 acc0 = {0.f, 0.f, 0.f, 0.f};
    f32x4 acc1 = {0.f, 0.f, 0.f, 0.f};
    float m = -1e30f, lsum = 0.f;   // lsum: per-lane partial (reduced at end)

    // staging decomposition (128 threads)
    const int kr = tid >> 2, kc = tid & 3;      // K: rows kr, kr+32; 16B chunk kc
    const int vp = tid & 31, vd = tid >> 5;     // V: key-pair vp, d-groups vd, vd+4

    short8  kreg0, kreg1;
    ushort4 va0, vc0, va1, vc1;

    #define LOAD_TILE(m0_)                                                          \
        {                                                                           \
            const int m0i = (m0_);                                                  \
            kreg0 = *reinterpret_cast<const short8*>(kb + (size_t)(m0i + kr) * C + h * DK + kc * 8);        \
            kreg1 = *reinterpret_cast<const short8*>(kb + (size_t)(m0i + 32 + kr) * C + h * DK + kc * 8);   \
            const ushort* v0 = vb + (size_t)(m0i + 2 * vp) * C + h * DK + vd * 4;   \
            va0 = *reinterpret_cast<const ushort4*>(v0);                            \
            vc0 = *reinterpret_cast<const ushort4*>(v0 + C);                        \
            va1 = *reinterpret_cast<const ushort4*>(v0 + 16);                       \
            vc1 = *reinterpret_cast<const ushort4*>(v0 + C + 16);                   \
        }

    LOAD_TILE(0);

    for (int t = 0; t < N / 64; ++t) {
        // ---- write staged tile to LDS (implicit vmcnt wait on regs)
        *reinterpret_cast<short8*>(Ks + kr * 40 + kc * 8) = kreg0;
        *reinterpret_cast<short8*>(Ks + (kr + 32) * 40 + kc * 8) = kreg1;
        {
            unsigned p0 = (unsigned)va0.x | ((unsigned)vc0.x << 16);
            unsigned p1 = (unsigned)va0.y | ((unsigned)vc0.y << 16);
            unsigned p2 = (unsigned)va0.z | ((unsigned)vc0.z << 16);
            unsigned p3 = (unsigned)va0.w | ((unsigned)vc0.w << 16);
            *reinterpret_cast<unsigned*>(Vt + (vd * 4 + 0) * 72 + 2 * vp) = p0;
            *reinterpret_cast<unsigned*>(Vt + (vd * 4 + 1) * 72 + 2 * vp) = p1;
            *reinterpret_cast<unsigned*>(Vt + (vd * 4 + 2) * 72 + 2 * vp) = p2;
            *reinterpret_cast<unsigned*>(Vt + (vd * 4 + 3) * 72 + 2 * vp) = p3;
            unsigned q0 = (unsigned)va1.x | ((unsigned)vc1.x << 16);
            unsigned q1 = (unsigned)va1.y | ((unsigned)vc1.y << 16);
            unsigned q2 = (unsigned)va1.z | ((unsigned)vc1.z << 16);
            unsigned q3 = (unsigned)va1.w | ((unsigned)vc1.w << 16);
            *reinterpret_cast<unsigned*>(Vt + (vd * 4 + 16) * 72 + 2 * vp) = q0;
            *reinterpret_cast<unsigned*>(Vt + (vd * 4 + 17) * 72 + 2 * vp) = q1;
            *reinterpret_cast<unsigned*>(Vt + (vd * 4 + 18) * 72 + 2 * vp) = q2;
            *reinterpret_cast<unsigned*>(Vt + (vd * 4 + 19) * 72 + 2 * vp) = q3;
        }
        __syncthreads();

        // ---- issue next tile's global loads (overlap with compute below)
        if (t < N / 64 - 1) LOAD_TILE((t + 1) * 64);

        // ---- QK^T (swapped): st[u][r] = S[key=16u+4g+r][q=lq]
        f32x4 st[4];
        __builtin_amdgcn_s_setprio(1);
        #pragma unroll
        for (int u = 0; u < 4; ++u) {
            short8 kf = *reinterpret_cast<const short8*>(Ks + (lq + 16 * u) * 40 + 8 * g);
            f32x4 z = {0.f, 0.f, 0.f, 0.f};
            st[u] = __builtin_amdgcn_mfma_f32_16x16x32_bf16(kf, qf, z, 0, 0, 0);
        }
        __builtin_amdgcn_s_setprio(0);

        // ---- online softmax, exp2 domain, defer-max
        float mxl = st[0][0];
        #pragma unroll
        for (int u = 0; u < 4; ++u)
            #pragma unroll
            for (int r = 0; r < 4; ++r) mxl = fmaxf(mxl, st[u][r]);

        if (!__all(mxl <= m + 8.0f)) {
            // rescale path (rare): reduce max across g-lanes, update state
            float mx = fmaxf(mxl, __shfl_xor(mxl, 16));
            mx = fmaxf(mx, __shfl_xor(mx, 32));
            float nm = fmaxf(m, mx);
            float corr = exp2f(m - nm);
            m = nm;
            lsum *= corr;
            float cw0 = __shfl(corr, 4 * g + 0);
            float cw1 = __shfl(corr, 4 * g + 1);
            float cw2 = __shfl(corr, 4 * g + 2);
            float cw3 = __shfl(corr, 4 * g + 3);
            acc0[0] *= cw0; acc0[1] *= cw1; acc0[2] *= cw2; acc0[3] *= cw3;
            acc1[0] *= cw0; acc1[1] *= cw1; acc1[2] *= cw2; acc1[3] *= cw3;
        }

        float ps = 0.f;
        uint2 pw[4];
        #pragma unroll
        for (int u = 0; u < 4; ++u) {
            float p0 = exp2f(st[u][0] - m);
            float p1 = exp2f(st[u][1] - m);
            float p2 = exp2f(st[u][2] - m);
            float p3 = exp2f(st[u][3] - m);
            ps += (p0 + p1) + (p2 + p3);
            pw[u].x = cvtpk(p0, p1);
            pw[u].y = cvtpk(p2, p3);
        }
        lsum += ps;

        #pragma unroll
        for (int u = 0; u < 4; ++u)
            *reinterpret_cast<uint2*>(Pl + lq * 72 + 4 * g + 16 * u) = pw[u];

        // ---- PV: O[q=4g+r][d=lq(+16)]
        short8 pf0 = *reinterpret_cast<const short8*>(Pl + lq * 72 + 8 * g);
        short8 pf1 = *reinterpret_cast<const short8*>(Pl + lq * 72 + 32 + 8 * g);
        __builtin_amdgcn_s_setprio(1);
        #pragma unroll
        for (int k2 = 0; k2 < 2; ++k2) {
            short8 pf = k2 ? pf1 : pf0;
            short8 vf0 = *reinterpret_cast<const short8*>(Vt + lq * 72 + 32 * k2 + 8 * g);
            short8 vf1 = *reinterpret_cast<const short8*>(Vt + (lq + 16) * 72 + 32 * k2 + 8 * g);
            acc0 = __builtin_amdgcn_mfma_f32_16x16x32_bf16(pf, vf0, acc0, 0, 0, 0);
            acc1 = __builtin_amdgcn_mfma_f32_16x16x32_bf16(pf, vf1, acc1, 0, 0, 0);
        }
        __builtin_amdgcn_s_setprio(0);
        __syncthreads();
    }

    // ---- epilogue: reduce lsum, normalize, transpose via LDS, residual add
    lsum += __shfl_xor(lsum, 16);
    lsum += __shfl_xor(lsum, 32);
    const float iv = 1.0f / lsum;
    float iw0 = __shfl(iv, 4 * g + 0);
    float iw1 = __shfl(iv, 4 * g + 1);
    float iw2 = __shfl(iv, 4 * g + 2);
    float iw3 = __shfl(iv, 4 * g + 3);

    Ost[(lq +  0) * 36 + wq * 16 + 4 * g + 0] = acc0[0] * iw0;
    Ost[(lq +  0) * 36 + wq * 16 + 4 * g + 1] = acc0[1] * iw1;
    Ost[(lq +  0) * 36 + wq * 16 + 4 * g + 2] = acc0[2] * iw2;
    Ost[(lq +  0) * 36 + wq * 16 + 4 * g + 3] = acc0[3] * iw3;
    Ost[(lq + 16) * 36 + wq * 16 + 4 * g + 0] = acc1[0] * iw0;
    Ost[(lq + 16) * 36 + wq * 16 + 4 * g + 1] = acc1[1] * iw1;
    Ost[(lq + 16) * 36 + wq * 16 + 4 * g + 2] = acc1[2] * iw2;
    Ost[(lq + 16) * 36 + wq * 16 + 4 * g + 3] = acc1[3] * iw3;
    __syncthreads();

    {
        const int d  = tid >> 2;          // 0..31
        const int nn = (tid & 3) * 8;     // 0,8,16,24
        const size_t go = ((size_t)b * C + h * DK + d) * (size_t)N + n0 + nn;
        float4 o1 = *reinterpret_cast<float4*>(Ost + d * 36 + nn);
        float4 o2 = *reinterpret_cast<float4*>(Ost + d * 36 + nn + 4);
        float4 x1 = *reinterpret_cast<const float4*>(x + go);
        float4 x2 = *reinterpret_cast<const float4*>(x + go + 4);
        *reinterpret_cast<float4*>(out + go)     = make_float4(o1.x + x1.x, o1.y + x1.y, o1.z + x1.z, o1.w + x1.w);
        *reinterpret_cast<float4*>(out + go + 4) = make_float4(o2.x + x2.x, o2.y + x2.y, o2.z + x2.z, o2.w + x2.w);
    }
}

extern "C" void kernel_launch(void* const* d_in, const int* in_sizes, int n_in,
                              void* d_out, int out_size, void* d_ws, size_t ws_size,
                              hipStream_t stream) {
    const float* x  = (const float*)d_in[0];
    const float* wq = (const float*)d_in[1];
    const float* wk = (const float*)d_in[2];
    const float* wv = (const float*)d_in[3];
    float* out = (float*)d_out;
    ushort* ws = (ushort*)d_ws;

    const size_t NC = (size_t)N * C;
    const size_t needFull = 3 * (size_t)B * NC * sizeof(ushort);   // 14.2 MB

    if (ws_size >= needFull) {
        proj_kernel<<<dim3((N / 64) * (C / 64), 3, B), 256, 0, stream>>>(
            x, wq, wk, wv, ws, -1, (size_t)B * NC, NC);
        attn_kernel<<<dim3(72 * NH * B), 128, 0, stream>>>(
            ws, x, out, -1, (size_t)B * NC, NC, 4);
    } else {
        // per-batch fallback (3.5 MB): proj_b -> attn_b serialized on stream
        for (int b = 0; b < B; ++b) {
            proj_kernel<<<dim3((N / 64) * (C / 64), 3, 1), 256, 0, stream>>>(
                x, wq, wk, wv, ws, b, NC, 0);
            attn_kernel<<<dim3(72 * NH), 128, 0, stream>>>(
                ws, x, out, b, NC, 0, 1);
        }
    }
}